// Round 2
// baseline (303.144 us; speedup 1.0000x reference)
//
#include <hip/hip_runtime.h>
#include <math.h>

#define NUM_POINTS 64
#define OUT_DIMS 128
#define BLOCK_THREADS 256
#define ELEMS_PER_BLOCK 256

__global__ __launch_bounds__(BLOCK_THREADS) void ce_kernel(
    const float* __restrict__ x,
    const float* __restrict__ emb,
    float* __restrict__ out) {
  __shared__ float s_emb[NUM_POINTS * OUT_DIMS];            // 32 KB
  __shared__ __align__(16) float s_w[ELEMS_PER_BLOCK * 8];  // 8 KB, normalized weights
  __shared__ int s_p0[ELEMS_PER_BLOCK];                     // 1 KB, clamped base row

  const int t = threadIdx.x;
  const int base = blockIdx.x * ELEMS_PER_BLOCK;

  // --- stage embeddings (32 KB) ---
  {
    float4* s4 = (float4*)s_emb;
    const float4* e4 = (const float4*)emb;
#pragma unroll
    for (int i = 0; i < (NUM_POINTS * OUT_DIMS / 4) / BLOCK_THREADS; ++i)
      s4[t + i * BLOCK_THREADS] = e4[t + i * BLOCK_THREADS];
  }

  // --- phase 1: one thread computes one element's normalized weights ---
  {
    const float xv = x[base + t];
    const float xs = (xv + 1.0f) * 32.0f;          // [0, 64]
    int p0 = (int)floorf(xs) - 3;
    int p0c = p0 < 0 ? 0 : (p0 > NUM_POINTS - 8 ? NUM_POINTS - 8 : p0);
    float w[8];
    float wsum = 0.0f;
#pragma unroll
    for (int j = 0; j < 8; ++j) {
      const float d = xs - (float)(p0c + j);
      // cos(pi*d/8) == cos(2*pi * d/16); v_cos_f32 takes revolutions
      const float c = __builtin_amdgcn_cosf(d * 0.0625f);
      float wv = c * c;
      // rect window: rows shifted in by clamping carry zero weight
      wv = (d > -4.0f && d < 4.0f) ? wv : 0.0f;
      w[j] = wv;
      wsum += wv;
    }
    const float inv = (wsum != 0.0f) ? __builtin_amdgcn_rcpf(wsum) : 0.0f;
#pragma unroll
    for (int j = 0; j < 8; ++j) w[j] *= inv;
    float4* wp = (float4*)&s_w[t * 8];
    wp[0] = make_float4(w[0], w[1], w[2], w[3]);
    wp[1] = make_float4(w[4], w[5], w[6], w[7]);
    s_p0[t] = p0c;
  }
  __syncthreads();

  // --- phase 2: gather-FMA. Half-wave (32 lanes) covers one element's 128 dims ---
  const int lane_chunk = t & 31;  // which float4 of the 128 dims
  const int sub = t >> 5;         // element offset within an iteration (0..7)

#pragma unroll 2
  for (int it = 0; it < ELEMS_PER_BLOCK / 8; ++it) {
    const int slot = it * 8 + sub;
    const int p0c = s_p0[slot];                       // broadcast read
    const float4* wp = (const float4*)&s_w[slot * 8]; // broadcast reads
    const float4 wa = wp[0];
    const float4 wb = wp[1];
    const float* rowp = s_emb + p0c * OUT_DIMS + lane_chunk * 4;

    float4 acc = make_float4(0.f, 0.f, 0.f, 0.f);
    const float wj[8] = {wa.x, wa.y, wa.z, wa.w, wb.x, wb.y, wb.z, wb.w};
#pragma unroll
    for (int j = 0; j < 8; ++j) {
      const float4 ev = *(const float4*)(rowp + j * OUT_DIMS);  // imm offset j*512B
      acc.x = fmaf(wj[j], ev.x, acc.x);
      acc.y = fmaf(wj[j], ev.y, acc.y);
      acc.z = fmaf(wj[j], ev.z, acc.z);
      acc.w = fmaf(wj[j], ev.w, acc.w);
    }
    ((float4*)(out + (size_t)(base + slot) * OUT_DIMS))[lane_chunk] = acc;
  }
}

extern "C" void kernel_launch(void* const* d_in, const int* in_sizes, int n_in,
                              void* d_out, int out_size, void* d_ws, size_t ws_size,
                              hipStream_t stream) {
  const float* x = (const float*)d_in[0];    // (64, 8192) fp32
  const float* emb = (const float*)d_in[1];  // (64, 128) fp32
  float* out = (float*)d_out;                // (64, 8192, 128) fp32

  const int n = in_sizes[0];                 // 524288
  const int blocks = n / ELEMS_PER_BLOCK;    // 2048
  ce_kernel<<<blocks, BLOCK_THREADS, 0, stream>>>(x, emb, out);
}